// Round 15
// baseline (123.595 us; speedup 1.0000x reference)
//
#include <hip/hip_runtime.h>
#include <math.h>

#define NN 20000
#define EE 320000

using short8 = __attribute__((ext_vector_type(8))) short;
using f32x4  = __attribute__((ext_vector_type(4))) float;
using u16x4  = __attribute__((ext_vector_type(4))) unsigned short;

__device__ __forceinline__ unsigned short f2bf(float x) {
    union { float f; unsigned u; } v; v.f = x;
    unsigned r = (v.u + 0x7fffu + ((v.u >> 16) & 1u)) >> 16;
    return (unsigned short)r;
}
__device__ __forceinline__ float bf2f(unsigned short b) {
    union { unsigned u; float f; } v; v.u = ((unsigned)b) << 16;
    return v.f;
}
__device__ __forceinline__ float sigmoidf_(float x) { return 1.f / (1.f + __expf(-x)); }
__device__ __forceinline__ float tanhf_(float x) {
    float e = __expf(-2.f * x);
    return (1.f - e) / (1.f + e);
}
__device__ __forceinline__ float lrelu_(float x) { return x > 0.f ? x : 0.2f * x; }
__device__ __forceinline__ float elu_(float x) { return x > 0.f ? x : __expf(x) - 1.f; }

// ---------------- weight pack into MFMA B-fragment layout ----------------
struct PackDesc { const float* w; unsigned short* out; int O; int ldw; int mode; };
struct PackArgs { PackDesc d[10]; };

__global__ void k_pack(PackArgs args) {
    PackDesc d = args.d[blockIdx.y];
    int idx = blockIdx.x * 256 + threadIdx.x;
    if (d.mode == 1) {   // W2b: bond part of fc2_w, K=32 zero-padded
        if (idx >= 512) return;
        int t = idx >> 6, l = idx & 63;
        int lr = l & 15, lg = l >> 4;
        int ch = lr * 8 + t;
        short8 o;
        #pragma unroll
        for (int j = 0; j < 8; j++) {
            int k = lg * 8 + j;
            o[j] = (k < 16) ? (short)f2bf(d.w[(size_t)ch * 144 + 128 + k]) : (short)0;
        }
        *(short8*)(d.out + (size_t)idx * 8) = o;
        return;
    }
    int total = (d.O / 16) * 4 * 64;
    if (idx >= total) return;
    int l = idx & 63, rest = idx >> 6;
    int ko = rest & 3, no = rest >> 2;
    int row = no * 16 + (l & 15);
    int col0 = ko * 32 + ((l >> 4) * 8);
    const float* src = d.w + (size_t)row * d.ldw + col0;
    unsigned short o[8];
    #pragma unroll
    for (int j = 0; j < 8; j++) o[j] = f2bf(src[j]);
    #pragma unroll
    for (int j = 0; j < 8; j++) d.out[(size_t)idx * 8 + j] = o[j];
}

// ---------------- V1 front ----------------
__global__ __launch_bounds__(256) void k_v1_front(
    const float* __restrict__ atom,
    const unsigned short* __restrict__ Bfc1, const unsigned short* __restrict__ BW2a,
    const float* __restrict__ fc1_b, const float* __restrict__ fc2_b,
    const float* __restrict__ attw,
    float* __restrict__ g0, unsigned short* __restrict__ naBf,
    unsigned short* __restrict__ Ubf, float* __restrict__ adst)
{
    __shared__ float Xs[16][132];
    __shared__ unsigned short Ys2[16 * 128];
    const int tid = threadIdx.x, l = tid & 63, w = tid >> 6;
    const int lr = l & 15, lg = l >> 4;
    const int m0 = blockIdx.x * 16;

    f32x4 acc1[2] = {}, accU[2] = {};
    #pragma unroll
    for (int ko = 0; ko < 4; ko++) {
        const f32x4* ap = (const f32x4*)(atom + (size_t)(m0 + lr) * 128 + ko * 32 + lg * 8);
        f32x4 a0 = __builtin_nontemporal_load(ap);
        f32x4 a1 = __builtin_nontemporal_load(ap + 1);
        short8 af;
        #pragma unroll
        for (int j = 0; j < 4; j++) { af[j] = (short)f2bf(a0[j]); af[4 + j] = (short)f2bf(a1[j]); }
        #pragma unroll
        for (int i = 0; i < 2; i++) {
            int t = w * 2 + i;
            short8 b1 = *(const short8*)(Bfc1 + ((size_t)(t * 4 + ko) * 64 + l) * 8);
            acc1[i] = __builtin_amdgcn_mfma_f32_16x16x32_bf16(af, b1, acc1[i], 0, 0, 0);
            short8 bu = *(const short8*)(BW2a + ((size_t)(t * 4 + ko) * 64 + l) * 8);
            accU[i] = __builtin_amdgcn_mfma_f32_16x16x32_bf16(af, bu, accU[i], 0, 0, 0);
        }
    }
    #pragma unroll
    for (int i = 0; i < 2; i++) {
        int col = (w * 2 + i) * 16 + lr;
        float b1v = fc1_b[col], bUv = fc2_b[col];
        #pragma unroll
        for (int r = 0; r < 4; r++) {
            int row = lg * 4 + r;
            float v = lrelu_(acc1[i][r] + b1v);
            Xs[row][col] = v;
            Ys2[row * 128 + col] = f2bf(accU[i][r] + bUv);
        }
    }
    __syncthreads();
    *(short8*)(Ubf + (size_t)m0 * 128 + tid * 8) = *(const short8*)(Ys2 + tid * 8);
    {
        int row = tid >> 4, q = tid & 15;
        short8 tmp;
        float p = 0.f;
        float vv[8];
        #pragma unroll
        for (int j = 0; j < 8; j++) {
            float x = Xs[row][q * 8 + j];
            vv[j] = x;
            tmp[j] = (short)f2bf(x);
            p = fmaf(x, attw[q * 8 + j], p);
        }
        __builtin_nontemporal_store(*(f32x4*)vv,
            (f32x4*)(g0 + (size_t)(m0 + row) * 128 + q * 8));
        __builtin_nontemporal_store(*(f32x4*)(vv + 4),
            (f32x4*)(g0 + (size_t)(m0 + row) * 128 + q * 8 + 4));
        *(short8*)(naBf + (size_t)(m0 + row) * 128 + q * 8) = tmp;
        #pragma unroll
        for (int m = 1; m <= 8; m <<= 1) p += __shfl_xor(p, m, 16);
        if (q == 0) adst[m0 + row] = p;
    }
}

// ---------------- GRU: 16-row blocks, 512 threads (8 waves) ----------------
// AGGMODE 0 (V1): fused edge logits (bond MFMA + U decomposition) -> lgS.
// AGGMODE 1 (V2): inline logits aD[dst]+bS[src]+b.
// Overlap region: softmax -> ISSUE 16 gather loads -> hh GEMMs (independent of agg)
//   -> accumulate gather -> aggS. Then pre-GEMM -> ctxS -> ih GEMMs + gates.
// FRONT: next-layer aD/bS dots. FINAL: avg + lin + gelu.
template<int AGGMODE, int FRONT, int FINAL>
__global__ __launch_bounds__(512, 4) void k_gru(
    const float* __restrict__ aD, const float* __restrict__ bS, const float* __restrict__ b1,
    const float* __restrict__ bond, const unsigned short* __restrict__ BW2b,
    const float* __restrict__ attw, const float* __restrict__ attb1,
    const float* __restrict__ adst, const unsigned short* __restrict__ U,
    const int* __restrict__ esrc, const unsigned short* __restrict__ V,
    const unsigned short* __restrict__ Bpre, const float* __restrict__ bpre,
    const unsigned short* __restrict__ Bih, const unsigned short* __restrict__ Bhh,
    const float* __restrict__ bih, const float* __restrict__ bhh,
    const unsigned short* __restrict__ hprevBf, float* __restrict__ houtF,
    unsigned short* __restrict__ houtBf,
    const float* __restrict__ w2att, float* __restrict__ aDOut, float* __restrict__ bSOut,
    const float* __restrict__ as0, const float* __restrict__ as1,
    const unsigned short* __restrict__ Blin, const float* __restrict__ linb,
    float* __restrict__ avgOut, float* __restrict__ outF)
{
    __shared__ unsigned short aggS[16][136];
    __shared__ unsigned short ctxS[16][136];
    __shared__ unsigned short hpS[16][136];
    __shared__ float lgS[(AGGMODE == 0) ? 16 : 1][16];
    const int tid = threadIdx.x, l = tid & 63, w = tid >> 6;   // w in 0..7
    const int lr = l & 15, lg = l >> 4;
    const int m0 = blockIdx.x * 16;
    const int r2 = tid >> 5, c4 = (tid & 31) * 4;              // 32-thread/row staging map

    // stage bf16 hprev (coalesced) into hpS
    *(u16x4*)&hpS[r2][c4] = *(const u16x4*)(hprevBf + (size_t)(m0 + r2) * 128 + c4);

    if (AGGMODE == 0) {
        // ---- fused V1 edge logits: wave w handles nodes m0 + w*2 + 0..1 ----
        float aw[8];
        #pragma unroll
        for (int t = 0; t < 8; t++) aw[t] = attw[128 + lr * 8 + t];
        const float ab = attb1[0];
        #pragma unroll
        for (int nn = 0; nn < 2; nn++) {
            const int n = m0 + w * 2 + nn;
            const int e0 = n * 16;
            short8 af = {};
            if (lg < 2) {
                const f32x4* bp = (const f32x4*)(bond + (size_t)(e0 + lr) * 16 + lg * 8);
                f32x4 b0 = __builtin_nontemporal_load(bp);
                f32x4 b1v = __builtin_nontemporal_load(bp + 1);
                #pragma unroll
                for (int j = 0; j < 4; j++) {
                    af[j] = (short)f2bf(b0[j]); af[4 + j] = (short)f2bf(b1v[j]);
                }
            }
            f32x4 c[8];
            #pragma unroll
            for (int t = 0; t < 8; t++) {
                short8 bw = *(const short8*)(BW2b + (size_t)(t * 64 + l) * 8);
                f32x4 z = {};
                c[t] = __builtin_amdgcn_mfma_f32_16x16x32_bf16(af, bw, z, 0, 0, 0);
            }
            float s[4];
            #pragma unroll
            for (int r = 0; r < 4; r++) {
                int e = e0 + lg * 4 + r;
                int src = esrc[e];
                short8 u = *(const short8*)(U + (size_t)src * 128 + lr * 8);
                float a0 = 0.f;
                #pragma unroll
                for (int t = 0; t < 8; t++)
                    a0 = fmaf(aw[t], lrelu_(c[t][r] + bf2f((unsigned short)u[t])), a0);
                s[r] = a0;
            }
            #pragma unroll
            for (int mk = 1; mk <= 8; mk <<= 1)
                #pragma unroll
                for (int r = 0; r < 4; r++) s[r] += __shfl_xor(s[r], mk, 16);
            if (lr == 0) {
                float anode = adst[n];
                #pragma unroll
                for (int r = 0; r < 4; r++)
                    lgS[w * 2 + nn][lg * 4 + r] = lrelu_(anode + ab + s[r]);
            }
        }
    }
    __syncthreads();   // hpS (and lgS) ready

    // ---- softmax (32 threads/node = 16 edge-lanes x 2 channel-halves) ----
    const int g2 = tid >> 5;          // node 0..15
    const int q2 = tid & 31;
    const int q = q2 & 15;            // edge lane
    const int hf = q2 >> 4;           // channel half
    float wq;
    int srcq;
    {
        const int gnode = m0 + g2;
        const int e = gnode * 16 + q;
        srcq = esrc[e];
        float lgt;
        if (AGGMODE == 0) lgt = lgS[g2][q];
        else              lgt = lrelu_(aD[gnode] + bS[srcq] + b1[0]);
        float mx = lgt;
        #pragma unroll
        for (int mk = 1; mk <= 8; mk <<= 1) mx = fmaxf(mx, __shfl_xor(mx, mk, 16));
        float ex = __expf(lgt - mx);
        float den = ex;
        #pragma unroll
        for (int mk = 1; mk <= 8; mk <<= 1) den += __shfl_xor(den, mk, 16);
        wq = ex / den;
    }

    // ---- ISSUE all 16 gather loads (in-flight across the hh GEMMs) ----
    u16x4 gv[16];
    #pragma unroll
    for (int i = 0; i < 16; i++) {
        int si = __shfl(srcq, i, 16);
        gv[i] = *(const u16x4*)(V + (size_t)si * 128 + hf * 64 + q * 4);
    }

    // ---- hh GEMMs (depend only on hpS) — hide gather latency here ----
    f32x4 ah[3] = {};
    #pragma unroll
    for (int ko = 0; ko < 4; ko++) {
        short8 afh = *(const short8*)&hpS[lr][ko * 32 + lg * 8];
        #pragma unroll
        for (int g = 0; g < 3; g++) {
            short8 bh = *(const short8*)(Bhh + ((size_t)((w + 8 * g) * 4 + ko) * 64 + l) * 8);
            ah[g] = __builtin_amdgcn_mfma_f32_16x16x32_bf16(afh, bh, ah[g], 0, 0, 0);
        }
    }

    // ---- accumulate gather -> aggS ----
    {
        float s[4] = {};
        #pragma unroll
        for (int i = 0; i < 16; i++) {
            float wi = __shfl(wq, i, 16);
            #pragma unroll
            for (int j = 0; j < 4; j++) s[j] = fmaf(wi, bf2f(gv[i][j]), s[j]);
        }
        u16x4 o;
        #pragma unroll
        for (int j = 0; j < 4; j++) o[j] = f2bf(s[j]);
        *(u16x4*)&aggS[g2][hf * 64 + q * 4] = o;
    }
    __syncthreads();   // aggS ready

    // ---- pre-GEMM: ctx = elu(aggS @ Wpre^T + b) ----
    f32x4 accp = {};
    #pragma unroll
    for (int ko = 0; ko < 4; ko++) {
        short8 afA = *(const short8*)&aggS[lr][ko * 32 + lg * 8];
        short8 bfp = *(const short8*)(Bpre + ((size_t)(w * 4 + ko) * 64 + l) * 8);
        accp = __builtin_amdgcn_mfma_f32_16x16x32_bf16(afA, bfp, accp, 0, 0, 0);
    }
    {
        const int col = w * 16 + lr;
        const float bb = bpre[col];
        #pragma unroll
        for (int r = 0; r < 4; r++)
            ctxS[lg * 4 + r][col] = f2bf(elu_(accp[r] + bb));
    }
    __syncthreads();   // ctxS ready, all hpS A-frag reads done

    // ---- ih GEMMs + gates (ho -> hpS in place, bf16) ----
    f32x4 ai[3] = {};
    #pragma unroll
    for (int ko = 0; ko < 4; ko++) {
        short8 afc = *(const short8*)&ctxS[lr][ko * 32 + lg * 8];
        #pragma unroll
        for (int g = 0; g < 3; g++) {
            short8 bi = *(const short8*)(Bih + ((size_t)((w + 8 * g) * 4 + ko) * 64 + l) * 8);
            ai[g] = __builtin_amdgcn_mfma_f32_16x16x32_bf16(afc, bi, ai[g], 0, 0, 0);
        }
    }
    {
        const int c = w * 16 + lr;
        const float br = bih[c] + bhh[c];
        const float bz = bih[c + 128] + bhh[c + 128];
        const float bin_ = bih[c + 256];
        const float bhn = bhh[c + 256];
        #pragma unroll
        for (int r = 0; r < 4; r++) {
            const int lrow = lg * 4 + r;
            float rg = sigmoidf_(ai[0][r] + ah[0][r] + br);
            float zg = sigmoidf_(ai[1][r] + ah[1][r] + bz);
            float ng = tanhf_(ai[2][r] + bin_ + rg * (ah[2][r] + bhn));
            float hp = bf2f(hpS[lrow][c]);
            hpS[lrow][c] = f2bf(fmaf(zg, hp - ng, ng));
        }
    }
    __syncthreads();   // hpS now holds ho (bf16)

    // ---- coalesced h writes: f32 stream nt, bf16 table cacheable ----
    {
        u16x4 hv = *(const u16x4*)&hpS[r2][c4];
        f32x4 vf;
        #pragma unroll
        for (int j = 0; j < 4; j++) vf[j] = bf2f(hv[j]);
        __builtin_nontemporal_store(vf, (f32x4*)(houtF + (size_t)(m0 + r2) * 128 + c4));
        if (FINAL == 0)
            *(u16x4*)(houtBf + (size_t)(m0 + r2) * 128 + c4) = hv;
    }

    if (FRONT) {
        if (tid < 256) {
            int row = tid >> 4, qq = tid & 15;
            short8 hv8 = *(const short8*)&hpS[row][qq * 8];
            float pa = 0.f, pb = 0.f;
            #pragma unroll
            for (int j = 0; j < 8; j++) {
                float x = bf2f((unsigned short)hv8[j]);
                pa = fmaf(x, w2att[qq * 8 + j], pa);
                pb = fmaf(x, w2att[128 + qq * 8 + j], pb);
            }
            #pragma unroll
            for (int m = 1; m <= 8; m <<= 1) {
                pa += __shfl_xor(pa, m, 16);
                pb += __shfl_xor(pb, m, 16);
            }
            if (qq == 0) { aDOut[m0 + row] = pa; bSOut[m0 + row] = pb; }
        }
    }

    if (FINAL) {
        // avg (coalesced, nt streams) -> avgOut + ctxS(bf16)
        {
            f32x4 x0 = __builtin_nontemporal_load(
                (const f32x4*)(as0 + (size_t)(m0 + r2) * 128 + c4));
            f32x4 x1 = __builtin_nontemporal_load(
                (const f32x4*)(as1 + (size_t)(m0 + r2) * 128 + c4));
            u16x4 hv = *(const u16x4*)&hpS[r2][c4];
            f32x4 av;
            #pragma unroll
            for (int j = 0; j < 4; j++)
                av[j] = (x0[j] + x1[j] + bf2f(hv[j])) * (1.f / 3.f);
            __builtin_nontemporal_store(av, (f32x4*)(avgOut + (size_t)(m0 + r2) * 128 + c4));
            u16x4 ab16;
            #pragma unroll
            for (int j = 0; j < 4; j++) ab16[j] = f2bf(av[j]);
            *(u16x4*)&ctxS[r2][c4] = ab16;
        }
        __syncthreads();
        // lin GEMM: wave w -> col-tile w
        f32x4 acc2 = {};
        #pragma unroll
        for (int ko = 0; ko < 4; ko++) {
            short8 af = *(const short8*)&ctxS[lr][ko * 32 + lg * 8];
            short8 bf = *(const short8*)(Blin + ((size_t)(w * 4 + ko) * 64 + l) * 8);
            acc2 = __builtin_amdgcn_mfma_f32_16x16x32_bf16(af, bf, acc2, 0, 0, 0);
        }
        // gelu -> stage bf16 into aggS (free after pre-GEMM)
        {
            const int col = w * 16 + lr;
            const float bb = linb[col];
            #pragma unroll
            for (int r = 0; r < 4; r++) {
                float vv = acc2[r] + bb;
                vv = 0.5f * vv * (1.f + erff(vv * 0.70710678118654752f));
                aggS[lg * 4 + r][col] = f2bf(vv);
            }
        }
        __syncthreads();
        {
            u16x4 ov = *(const u16x4*)&aggS[r2][c4];
            f32x4 vf;
            #pragma unroll
            for (int j = 0; j < 4; j++) vf[j] = bf2f(ov[j]);
            __builtin_nontemporal_store(vf, (f32x4*)(outF + (size_t)(m0 + r2) * 128 + c4));
        }
    }
}

extern "C" void kernel_launch(void* const* d_in, const int* in_sizes, int n_in,
                              void* d_out, int out_size, void* d_ws, size_t ws_size,
                              hipStream_t stream) {
    const float* atom     = (const float*)d_in[0];
    const int*   esrc     = (const int*)d_in[1];
    const float* bond     = (const float*)d_in[3];
    const float* fc1_w    = (const float*)d_in[4];
    const float* fc1_b    = (const float*)d_in[5];
    const float* fc2_w    = (const float*)d_in[6];
    const float* fc2_b    = (const float*)d_in[7];
    const float* att_w    = (const float*)d_in[8];
    const float* att_b    = (const float*)d_in[9];
    const float* attend_w = (const float*)d_in[10];
    const float* attend_b = (const float*)d_in[11];
    const float* gih1     = (const float*)d_in[12];
    const float* ghh1     = (const float*)d_in[13];
    const float* bih1     = (const float*)d_in[14];
    const float* bhh1     = (const float*)d_in[15];
    const float* fc1v2_w  = (const float*)d_in[16];
    const float* fc1v2_b  = (const float*)d_in[17];
    const float* fc2v2_w  = (const float*)d_in[18];
    const float* fc2v2_b  = (const float*)d_in[19];
    const float* gih2     = (const float*)d_in[20];
    const float* ghh2     = (const float*)d_in[21];
    const float* bih2     = (const float*)d_in[22];
    const float* bhh2     = (const float*)d_in[23];
    const float* lin_w    = (const float*)d_in[24];
    const float* lin_b    = (const float*)d_in[25];

    char* wsb = (char*)d_ws;
    size_t off = 0;
    auto allocB = [&](size_t bytes) {
        size_t o = off; off = (off + bytes + 255) & ~(size_t)255; return o;
    };
    unsigned short* Bfc1   = (unsigned short*)(wsb + allocB(128 * 128 * 2));
    unsigned short* Batt   = (unsigned short*)(wsb + allocB(128 * 128 * 2));
    unsigned short* BW2a   = (unsigned short*)(wsb + allocB(128 * 128 * 2));
    unsigned short* BW2b   = (unsigned short*)(wsb + allocB(512 * 8 * 2));
    unsigned short* Bgih1  = (unsigned short*)(wsb + allocB(384 * 128 * 2));
    unsigned short* Bghh1  = (unsigned short*)(wsb + allocB(384 * 128 * 2));
    unsigned short* Bfc2v2 = (unsigned short*)(wsb + allocB(128 * 128 * 2));
    unsigned short* Bgih2  = (unsigned short*)(wsb + allocB(384 * 128 * 2));
    unsigned short* Bghh2  = (unsigned short*)(wsb + allocB(384 * 128 * 2));
    unsigned short* Blin   = (unsigned short*)(wsb + allocB(128 * 128 * 2));
    unsigned short* naBf   = (unsigned short*)(wsb + allocB((size_t)NN * 128 * 2));
    unsigned short* Ubf    = (unsigned short*)(wsb + allocB((size_t)NN * 128 * 2));
    unsigned short* h1Bf   = (unsigned short*)(wsb + allocB((size_t)NN * 128 * 2));
    unsigned short* h2Bf   = (unsigned short*)(wsb + allocB((size_t)NN * 128 * 2));
    float* adst   = (float*)(wsb + allocB((size_t)NN * 4));
    float* aD     = (float*)(wsb + allocB((size_t)NN * 4));
    float* bS     = (float*)(wsb + allocB((size_t)NN * 4));
    (void)ws_size;

    float* out0 = (float*)d_out;
    float* as0  = out0 + (size_t)NN * 128;
    float* as1  = as0 + (size_t)NN * 128;
    float* as2  = as1 + (size_t)NN * 128;
    float* g0   = out0 + (size_t)4 * NN * 128;
    float* avg  = out0 + (size_t)5 * NN * 128;

    PackArgs pa;
    pa.d[0] = { fc1_w,    Bfc1,   128, 128, 0 };
    pa.d[1] = { attend_w, Batt,   128, 128, 0 };
    pa.d[2] = { fc2_w,    BW2a,   128, 144, 0 };
    pa.d[3] = { gih1,     Bgih1,  384, 128, 0 };
    pa.d[4] = { ghh1,     Bghh1,  384, 128, 0 };
    pa.d[5] = { fc2v2_w,  Bfc2v2, 128, 128, 0 };
    pa.d[6] = { gih2,     Bgih2,  384, 128, 0 };
    pa.d[7] = { ghh2,     Bghh2,  384, 128, 0 };
    pa.d[8] = { lin_w,    Blin,   128, 128, 0 };
    pa.d[9] = { fc2_w,    BW2b,   0,   0,   1 };
    k_pack<<<dim3(24, 10), 256, 0, stream>>>(pa);

    const int GB = NN / 16;     // 1250

    // ---- V1 front ----
    k_v1_front<<<GB, 256, 0, stream>>>(atom, Bfc1, BW2a, fc1_b, fc2_b, att_w,
                                       g0, naBf, Ubf, adst);
    // ---- V1: fused logits + agg + GRU + front(layer2) ----
    k_gru<0, 1, 0><<<GB, 512, 0, stream>>>(
        nullptr, nullptr, nullptr,
        bond, BW2b, att_w, att_b, adst, Ubf,
        esrc, naBf,
        Batt, attend_b,
        Bgih1, Bghh1, bih1, bhh1, naBf, as0, h1Bf,
        fc1v2_w, aD, bS,
        nullptr, nullptr, nullptr, nullptr, nullptr, nullptr);

    // ---- V2 layer 2 ----
    k_gru<1, 1, 0><<<GB, 512, 0, stream>>>(
        aD, bS, fc1v2_b,
        nullptr, nullptr, nullptr, nullptr, nullptr, nullptr,
        esrc, h1Bf,
        Bfc2v2, fc2v2_b,
        Bgih2, Bghh2, bih2, bhh2, h1Bf, as1, h2Bf,
        fc1v2_w, aD, bS,
        nullptr, nullptr, nullptr, nullptr, nullptr, nullptr);

    // ---- V2 layer 3 + final ----
    k_gru<1, 0, 1><<<GB, 512, 0, stream>>>(
        aD, bS, fc1v2_b,
        nullptr, nullptr, nullptr, nullptr, nullptr, nullptr,
        esrc, h2Bf,
        Bfc2v2, fc2v2_b,
        Bgih2, Bghh2, bih2, bhh2, h2Bf, as2, nullptr,
        nullptr, nullptr, nullptr,
        as0, as1, Blin, lin_b, avg, out0);
}

// Round 16
// 113.643 us; speedup vs baseline: 1.0876x; 1.0876x over previous
//
#include <hip/hip_runtime.h>
#include <math.h>

#define NN 20000
#define EE 320000

using short8 = __attribute__((ext_vector_type(8))) short;
using f32x4  = __attribute__((ext_vector_type(4))) float;
using f32x2  = __attribute__((ext_vector_type(2))) float;
using u16x4  = __attribute__((ext_vector_type(4))) unsigned short;

__device__ __forceinline__ unsigned short f2bf(float x) {
    union { float f; unsigned u; } v; v.f = x;
    unsigned r = (v.u + 0x7fffu + ((v.u >> 16) & 1u)) >> 16;
    return (unsigned short)r;
}
__device__ __forceinline__ float bf2f(unsigned short b) {
    union { unsigned u; float f; } v; v.u = ((unsigned)b) << 16;
    return v.f;
}
__device__ __forceinline__ float sigmoidf_(float x) { return 1.f / (1.f + __expf(-x)); }
__device__ __forceinline__ float tanhf_(float x) {
    float e = __expf(-2.f * x);
    return (1.f - e) / (1.f + e);
}
__device__ __forceinline__ float lrelu_(float x) { return x > 0.f ? x : 0.2f * x; }
__device__ __forceinline__ float elu_(float x) { return x > 0.f ? x : __expf(x) - 1.f; }

// fp8 e4m3 pack/unpack via HW converters
__device__ __forceinline__ unsigned pk_fp8x4(float a, float b, float c, float d) {
    int w = 0;
    w = __builtin_amdgcn_cvt_pk_fp8_f32(a, b, w, false);
    w = __builtin_amdgcn_cvt_pk_fp8_f32(c, d, w, true);
    return (unsigned)w;
}
__device__ __forceinline__ void up_fp8x4(unsigned w, float* o) {
    f32x2 lo = __builtin_amdgcn_cvt_pk_f32_fp8((int)w, false);
    f32x2 hi = __builtin_amdgcn_cvt_pk_f32_fp8((int)w, true);
    o[0] = lo[0]; o[1] = lo[1]; o[2] = hi[0]; o[3] = hi[1];
}

// ---------------- weight pack into MFMA B-fragment layout ----------------
struct PackDesc { const float* w; unsigned short* out; int O; int ldw; int mode; };
struct PackArgs { PackDesc d[10]; };

__global__ void k_pack(PackArgs args) {
    PackDesc d = args.d[blockIdx.y];
    int idx = blockIdx.x * 256 + threadIdx.x;
    if (d.mode == 1) {   // W2b: bond part of fc2_w, K=32 zero-padded
        if (idx >= 512) return;
        int t = idx >> 6, l = idx & 63;
        int lr = l & 15, lg = l >> 4;
        int ch = lr * 8 + t;
        short8 o;
        #pragma unroll
        for (int j = 0; j < 8; j++) {
            int k = lg * 8 + j;
            o[j] = (k < 16) ? (short)f2bf(d.w[(size_t)ch * 144 + 128 + k]) : (short)0;
        }
        *(short8*)(d.out + (size_t)idx * 8) = o;
        return;
    }
    int total = (d.O / 16) * 4 * 64;
    if (idx >= total) return;
    int l = idx & 63, rest = idx >> 6;
    int ko = rest & 3, no = rest >> 2;
    int row = no * 16 + (l & 15);
    int col0 = ko * 32 + ((l >> 4) * 8);
    const float* src = d.w + (size_t)row * d.ldw + col0;
    unsigned short o[8];
    #pragma unroll
    for (int j = 0; j < 8; j++) o[j] = f2bf(src[j]);
    #pragma unroll
    for (int j = 0; j < 8; j++) d.out[(size_t)idx * 8 + j] = o[j];
}

// ---------------- V1 front ----------------
__global__ __launch_bounds__(256) void k_v1_front(
    const float* __restrict__ atom,
    const unsigned short* __restrict__ Bfc1, const unsigned short* __restrict__ BW2a,
    const float* __restrict__ fc1_b, const float* __restrict__ fc2_b,
    const float* __restrict__ attw,
    float* __restrict__ g0, unsigned short* __restrict__ naBf,
    unsigned char* __restrict__ naF8,
    unsigned char* __restrict__ U8, float* __restrict__ adst)
{
    __shared__ float Xs[16][132];
    __shared__ unsigned short Ys2[16 * 128];
    const int tid = threadIdx.x, l = tid & 63, w = tid >> 6;
    const int lr = l & 15, lg = l >> 4;
    const int m0 = blockIdx.x * 16;

    f32x4 acc1[2] = {}, accU[2] = {};
    #pragma unroll
    for (int ko = 0; ko < 4; ko++) {
        const f32x4* ap = (const f32x4*)(atom + (size_t)(m0 + lr) * 128 + ko * 32 + lg * 8);
        f32x4 a0 = __builtin_nontemporal_load(ap);
        f32x4 a1 = __builtin_nontemporal_load(ap + 1);
        short8 af;
        #pragma unroll
        for (int j = 0; j < 4; j++) { af[j] = (short)f2bf(a0[j]); af[4 + j] = (short)f2bf(a1[j]); }
        #pragma unroll
        for (int i = 0; i < 2; i++) {
            int t = w * 2 + i;
            short8 b1 = *(const short8*)(Bfc1 + ((size_t)(t * 4 + ko) * 64 + l) * 8);
            acc1[i] = __builtin_amdgcn_mfma_f32_16x16x32_bf16(af, b1, acc1[i], 0, 0, 0);
            short8 bu = *(const short8*)(BW2a + ((size_t)(t * 4 + ko) * 64 + l) * 8);
            accU[i] = __builtin_amdgcn_mfma_f32_16x16x32_bf16(af, bu, accU[i], 0, 0, 0);
        }
    }
    #pragma unroll
    for (int i = 0; i < 2; i++) {
        int col = (w * 2 + i) * 16 + lr;
        float b1v = fc1_b[col], bUv = fc2_b[col];
        #pragma unroll
        for (int r = 0; r < 4; r++) {
            int row = lg * 4 + r;
            float v = lrelu_(acc1[i][r] + b1v);
            Xs[row][col] = v;
            Ys2[row * 128 + col] = f2bf(accU[i][r] + bUv);
        }
    }
    __syncthreads();
    {   // U in fp8 (gather table)
        short8 uy = *(const short8*)(Ys2 + tid * 8);
        float uf[8];
        #pragma unroll
        for (int j = 0; j < 8; j++) uf[j] = bf2f((unsigned short)uy[j]);
        uint2 o8;
        o8.x = pk_fp8x4(uf[0], uf[1], uf[2], uf[3]);
        o8.y = pk_fp8x4(uf[4], uf[5], uf[6], uf[7]);
        *(uint2*)(U8 + (size_t)m0 * 128 + tid * 8) = o8;
    }
    {
        int row = tid >> 4, q = tid & 15;
        short8 tmp;
        float p = 0.f;
        float vv[8];
        #pragma unroll
        for (int j = 0; j < 8; j++) {
            float x = Xs[row][q * 8 + j];
            vv[j] = x;
            tmp[j] = (short)f2bf(x);
            p = fmaf(x, attw[q * 8 + j], p);
        }
        __builtin_nontemporal_store(*(f32x4*)vv,
            (f32x4*)(g0 + (size_t)(m0 + row) * 128 + q * 8));
        __builtin_nontemporal_store(*(f32x4*)(vv + 4),
            (f32x4*)(g0 + (size_t)(m0 + row) * 128 + q * 8 + 4));
        *(short8*)(naBf + (size_t)(m0 + row) * 128 + q * 8) = tmp;
        uint2 n8;
        n8.x = pk_fp8x4(vv[0], vv[1], vv[2], vv[3]);
        n8.y = pk_fp8x4(vv[4], vv[5], vv[6], vv[7]);
        *(uint2*)(naF8 + (size_t)(m0 + row) * 128 + q * 8) = n8;
        #pragma unroll
        for (int m = 1; m <= 8; m <<= 1) p += __shfl_xor(p, m, 16);
        if (q == 0) adst[m0 + row] = p;
    }
}

// ---------------- GRU: 16-row blocks, 512 threads (8 waves), fp8 gather tables ----
// AGGMODE 0 (V1): fused edge logits (bond MFMA + fp8 U decomposition) -> lgS.
// AGGMODE 1 (V2): inline logits aD[dst]+bS[src]+b.
// softmax -> issue fp8 gather -> hh GEMMs overlap -> aggS -> pre-GEMM -> ih + gates.
template<int AGGMODE, int FRONT, int FINAL>
__global__ __launch_bounds__(512, 4) void k_gru(
    const float* __restrict__ aD, const float* __restrict__ bS, const float* __restrict__ b1,
    const float* __restrict__ bond, const unsigned short* __restrict__ BW2b,
    const float* __restrict__ attw, const float* __restrict__ attb1,
    const float* __restrict__ adst, const unsigned char* __restrict__ U8,
    const int* __restrict__ esrc, const unsigned char* __restrict__ V8,
    const unsigned short* __restrict__ Bpre, const float* __restrict__ bpre,
    const unsigned short* __restrict__ Bih, const unsigned short* __restrict__ Bhh,
    const float* __restrict__ bih, const float* __restrict__ bhh,
    const unsigned short* __restrict__ hprevBf, float* __restrict__ houtF,
    unsigned short* __restrict__ houtBf, unsigned char* __restrict__ houtF8,
    const float* __restrict__ w2att, float* __restrict__ aDOut, float* __restrict__ bSOut,
    const float* __restrict__ as0, const float* __restrict__ as1,
    const unsigned short* __restrict__ Blin, const float* __restrict__ linb,
    float* __restrict__ avgOut, float* __restrict__ outF)
{
    __shared__ unsigned short aggS[16][136];
    __shared__ unsigned short ctxS[16][136];
    __shared__ unsigned short hpS[16][136];
    __shared__ float lgS[(AGGMODE == 0) ? 16 : 1][16];
    const int tid = threadIdx.x, l = tid & 63, w = tid >> 6;   // w in 0..7
    const int lr = l & 15, lg = l >> 4;
    const int m0 = blockIdx.x * 16;
    const int r2 = tid >> 5, c4 = (tid & 31) * 4;              // 32-thread/row staging map

    // stage bf16 hprev (coalesced) into hpS
    *(u16x4*)&hpS[r2][c4] = *(const u16x4*)(hprevBf + (size_t)(m0 + r2) * 128 + c4);

    if (AGGMODE == 0) {
        // ---- fused V1 edge logits: wave w handles nodes m0 + w*2 + 0..1 ----
        float aw[8];
        #pragma unroll
        for (int t = 0; t < 8; t++) aw[t] = attw[128 + lr * 8 + t];
        const float ab = attb1[0];
        #pragma unroll
        for (int nn = 0; nn < 2; nn++) {
            const int n = m0 + w * 2 + nn;
            const int e0 = n * 16;
            short8 af = {};
            if (lg < 2) {
                const f32x4* bp = (const f32x4*)(bond + (size_t)(e0 + lr) * 16 + lg * 8);
                f32x4 b0 = __builtin_nontemporal_load(bp);
                f32x4 b1v = __builtin_nontemporal_load(bp + 1);
                #pragma unroll
                for (int j = 0; j < 4; j++) {
                    af[j] = (short)f2bf(b0[j]); af[4 + j] = (short)f2bf(b1v[j]);
                }
            }
            f32x4 c[8];
            #pragma unroll
            for (int t = 0; t < 8; t++) {
                short8 bw = *(const short8*)(BW2b + (size_t)(t * 64 + l) * 8);
                f32x4 z = {};
                c[t] = __builtin_amdgcn_mfma_f32_16x16x32_bf16(af, bw, z, 0, 0, 0);
            }
            float s[4];
            #pragma unroll
            for (int r = 0; r < 4; r++) {
                int e = e0 + lg * 4 + r;
                int src = esrc[e];
                uint2 u2 = *(const uint2*)(U8 + (size_t)src * 128 + lr * 8);
                float uf[8];
                up_fp8x4(u2.x, uf);
                up_fp8x4(u2.y, uf + 4);
                float a0 = 0.f;
                #pragma unroll
                for (int t = 0; t < 8; t++)
                    a0 = fmaf(aw[t], lrelu_(c[t][r] + uf[t]), a0);
                s[r] = a0;
            }
            #pragma unroll
            for (int mk = 1; mk <= 8; mk <<= 1)
                #pragma unroll
                for (int r = 0; r < 4; r++) s[r] += __shfl_xor(s[r], mk, 16);
            if (lr == 0) {
                float anode = adst[n];
                #pragma unroll
                for (int r = 0; r < 4; r++)
                    lgS[w * 2 + nn][lg * 4 + r] = lrelu_(anode + ab + s[r]);
            }
        }
    }
    __syncthreads();   // hpS (and lgS) ready

    // ---- softmax (32 threads/node = 16 edge-lanes x 2 channel-halves) ----
    const int g2 = tid >> 5;          // node 0..15
    const int q2 = tid & 31;
    const int q = q2 & 15;            // edge lane
    const int hf = q2 >> 4;           // channel half
    float wq;
    int srcq;
    {
        const int gnode = m0 + g2;
        const int e = gnode * 16 + q;
        srcq = esrc[e];
        float lgt;
        if (AGGMODE == 0) lgt = lgS[g2][q];
        else              lgt = lrelu_(aD[gnode] + bS[srcq] + b1[0]);
        float mx = lgt;
        #pragma unroll
        for (int mk = 1; mk <= 8; mk <<= 1) mx = fmaxf(mx, __shfl_xor(mx, mk, 16));
        float ex = __expf(lgt - mx);
        float den = ex;
        #pragma unroll
        for (int mk = 1; mk <= 8; mk <<= 1) den += __shfl_xor(den, mk, 16);
        wq = ex / den;
    }

    // ---- ISSUE all 16 fp8 gather loads (in flight across hh GEMMs) ----
    unsigned gv[16];
    #pragma unroll
    for (int i = 0; i < 16; i++) {
        int si = __shfl(srcq, i, 16);
        gv[i] = *(const unsigned*)(V8 + (size_t)si * 128 + hf * 64 + q * 4);
    }

    // ---- hh GEMMs (depend only on hpS) ----
    f32x4 ah[3] = {};
    #pragma unroll
    for (int ko = 0; ko < 4; ko++) {
        short8 afh = *(const short8*)&hpS[lr][ko * 32 + lg * 8];
        #pragma unroll
        for (int g = 0; g < 3; g++) {
            short8 bh = *(const short8*)(Bhh + ((size_t)((w + 8 * g) * 4 + ko) * 64 + l) * 8);
            ah[g] = __builtin_amdgcn_mfma_f32_16x16x32_bf16(afh, bh, ah[g], 0, 0, 0);
        }
    }

    // ---- accumulate gather -> aggS ----
    {
        float s[4] = {};
        #pragma unroll
        for (int i = 0; i < 16; i++) {
            float wi = __shfl(wq, i, 16);
            float d[4];
            up_fp8x4(gv[i], d);
            #pragma unroll
            for (int j = 0; j < 4; j++) s[j] = fmaf(wi, d[j], s[j]);
        }
        u16x4 o;
        #pragma unroll
        for (int j = 0; j < 4; j++) o[j] = f2bf(s[j]);
        *(u16x4*)&aggS[g2][hf * 64 + q * 4] = o;
    }
    __syncthreads();   // aggS ready

    // ---- pre-GEMM: ctx = elu(aggS @ Wpre^T + b) ----
    f32x4 accp = {};
    #pragma unroll
    for (int ko = 0; ko < 4; ko++) {
        short8 afA = *(const short8*)&aggS[lr][ko * 32 + lg * 8];
        short8 bfp = *(const short8*)(Bpre + ((size_t)(w * 4 + ko) * 64 + l) * 8);
        accp = __builtin_amdgcn_mfma_f32_16x16x32_bf16(afA, bfp, accp, 0, 0, 0);
    }
    {
        const int col = w * 16 + lr;
        const float bb = bpre[col];
        #pragma unroll
        for (int r = 0; r < 4; r++)
            ctxS[lg * 4 + r][col] = f2bf(elu_(accp[r] + bb));
    }
    __syncthreads();   // ctxS ready, all hpS A-frag reads done

    // ---- ih GEMMs + gates (ho -> hpS in place, bf16) ----
    f32x4 ai[3] = {};
    #pragma unroll
    for (int ko = 0; ko < 4; ko++) {
        short8 afc = *(const short8*)&ctxS[lr][ko * 32 + lg * 8];
        #pragma unroll
        for (int g = 0; g < 3; g++) {
            short8 bi = *(const short8*)(Bih + ((size_t)((w + 8 * g) * 4 + ko) * 64 + l) * 8);
            ai[g] = __builtin_amdgcn_mfma_f32_16x16x32_bf16(afc, bi, ai[g], 0, 0, 0);
        }
    }
    {
        const int c = w * 16 + lr;
        const float br = bih[c] + bhh[c];
        const float bz = bih[c + 128] + bhh[c + 128];
        const float bin_ = bih[c + 256];
        const float bhn = bhh[c + 256];
        #pragma unroll
        for (int r = 0; r < 4; r++) {
            const int lrow = lg * 4 + r;
            float rg = sigmoidf_(ai[0][r] + ah[0][r] + br);
            float zg = sigmoidf_(ai[1][r] + ah[1][r] + bz);
            float ng = tanhf_(ai[2][r] + bin_ + rg * (ah[2][r] + bhn));
            float hp = bf2f(hpS[lrow][c]);
            hpS[lrow][c] = f2bf(fmaf(zg, hp - ng, ng));
        }
    }
    __syncthreads();   // hpS now holds ho (bf16)

    // ---- coalesced h writes: f32 stream nt, bf16 + fp8 tables cacheable ----
    {
        u16x4 hv = *(const u16x4*)&hpS[r2][c4];
        f32x4 vf;
        #pragma unroll
        for (int j = 0; j < 4; j++) vf[j] = bf2f(hv[j]);
        __builtin_nontemporal_store(vf, (f32x4*)(houtF + (size_t)(m0 + r2) * 128 + c4));
        if (FINAL == 0) {
            *(u16x4*)(houtBf + (size_t)(m0 + r2) * 128 + c4) = hv;
            *(unsigned*)(houtF8 + (size_t)(m0 + r2) * 128 + c4) =
                pk_fp8x4(vf[0], vf[1], vf[2], vf[3]);
        }
    }

    if (FRONT) {
        if (tid < 256) {
            int row = tid >> 4, qq = tid & 15;
            short8 hv8 = *(const short8*)&hpS[row][qq * 8];
            float pa = 0.f, pb = 0.f;
            #pragma unroll
            for (int j = 0; j < 8; j++) {
                float x = bf2f((unsigned short)hv8[j]);
                pa = fmaf(x, w2att[qq * 8 + j], pa);
                pb = fmaf(x, w2att[128 + qq * 8 + j], pb);
            }
            #pragma unroll
            for (int m = 1; m <= 8; m <<= 1) {
                pa += __shfl_xor(pa, m, 16);
                pb += __shfl_xor(pb, m, 16);
            }
            if (qq == 0) { aDOut[m0 + row] = pa; bSOut[m0 + row] = pb; }
        }
    }

    if (FINAL) {
        // avg (coalesced, nt streams) -> avgOut + ctxS(bf16)
        {
            f32x4 x0 = __builtin_nontemporal_load(
                (const f32x4*)(as0 + (size_t)(m0 + r2) * 128 + c4));
            f32x4 x1 = __builtin_nontemporal_load(
                (const f32x4*)(as1 + (size_t)(m0 + r2) * 128 + c4));
            u16x4 hv = *(const u16x4*)&hpS[r2][c4];
            f32x4 av;
            #pragma unroll
            for (int j = 0; j < 4; j++)
                av[j] = (x0[j] + x1[j] + bf2f(hv[j])) * (1.f / 3.f);
            __builtin_nontemporal_store(av, (f32x4*)(avgOut + (size_t)(m0 + r2) * 128 + c4));
            u16x4 ab16;
            #pragma unroll
            for (int j = 0; j < 4; j++) ab16[j] = f2bf(av[j]);
            *(u16x4*)&ctxS[r2][c4] = ab16;
        }
        __syncthreads();
        // lin GEMM: wave w -> col-tile w
        f32x4 acc2 = {};
        #pragma unroll
        for (int ko = 0; ko < 4; ko++) {
            short8 af = *(const short8*)&ctxS[lr][ko * 32 + lg * 8];
            short8 bf = *(const short8*)(Blin + ((size_t)(w * 4 + ko) * 64 + l) * 8);
            acc2 = __builtin_amdgcn_mfma_f32_16x16x32_bf16(af, bf, acc2, 0, 0, 0);
        }
        // gelu -> stage bf16 into aggS (free after pre-GEMM)
        {
            const int col = w * 16 + lr;
            const float bb = linb[col];
            #pragma unroll
            for (int r = 0; r < 4; r++) {
                float vv = acc2[r] + bb;
                vv = 0.5f * vv * (1.f + erff(vv * 0.70710678118654752f));
                aggS[lg * 4 + r][col] = f2bf(vv);
            }
        }
        __syncthreads();
        {
            u16x4 ov = *(const u16x4*)&aggS[r2][c4];
            f32x4 vf;
            #pragma unroll
            for (int j = 0; j < 4; j++) vf[j] = bf2f(ov[j]);
            __builtin_nontemporal_store(vf, (f32x4*)(outF + (size_t)(m0 + r2) * 128 + c4));
        }
    }
}

extern "C" void kernel_launch(void* const* d_in, const int* in_sizes, int n_in,
                              void* d_out, int out_size, void* d_ws, size_t ws_size,
                              hipStream_t stream) {
    const float* atom     = (const float*)d_in[0];
    const int*   esrc     = (const int*)d_in[1];
    const float* bond     = (const float*)d_in[3];
    const float* fc1_w    = (const float*)d_in[4];
    const float* fc1_b    = (const float*)d_in[5];
    const float* fc2_w    = (const float*)d_in[6];
    const float* fc2_b    = (const float*)d_in[7];
    const float* att_w    = (const float*)d_in[8];
    const float* att_b    = (const float*)d_in[9];
    const float* attend_w = (const float*)d_in[10];
    const float* attend_b = (const float*)d_in[11];
    const float* gih1     = (const float*)d_in[12];
    const float* ghh1     = (const float*)d_in[13];
    const float* bih1     = (const float*)d_in[14];
    const float* bhh1     = (const float*)d_in[15];
    const float* fc1v2_w  = (const float*)d_in[16];
    const float* fc1v2_b  = (const float*)d_in[17];
    const float* fc2v2_w  = (const float*)d_in[18];
    const float* fc2v2_b  = (const float*)d_in[19];
    const float* gih2     = (const float*)d_in[20];
    const float* ghh2     = (const float*)d_in[21];
    const float* bih2     = (const float*)d_in[22];
    const float* bhh2     = (const float*)d_in[23];
    const float* lin_w    = (const float*)d_in[24];
    const float* lin_b    = (const float*)d_in[25];

    char* wsb = (char*)d_ws;
    size_t off = 0;
    auto allocB = [&](size_t bytes) {
        size_t o = off; off = (off + bytes + 255) & ~(size_t)255; return o;
    };
    unsigned short* Bfc1   = (unsigned short*)(wsb + allocB(128 * 128 * 2));
    unsigned short* Batt   = (unsigned short*)(wsb + allocB(128 * 128 * 2));
    unsigned short* BW2a   = (unsigned short*)(wsb + allocB(128 * 128 * 2));
    unsigned short* BW2b   = (unsigned short*)(wsb + allocB(512 * 8 * 2));
    unsigned short* Bgih1  = (unsigned short*)(wsb + allocB(384 * 128 * 2));
    unsigned short* Bghh1  = (unsigned short*)(wsb + allocB(384 * 128 * 2));
    unsigned short* Bfc2v2 = (unsigned short*)(wsb + allocB(128 * 128 * 2));
    unsigned short* Bgih2  = (unsigned short*)(wsb + allocB(384 * 128 * 2));
    unsigned short* Bghh2  = (unsigned short*)(wsb + allocB(384 * 128 * 2));
    unsigned short* Blin   = (unsigned short*)(wsb + allocB(128 * 128 * 2));
    unsigned short* naBf   = (unsigned short*)(wsb + allocB((size_t)NN * 128 * 2));
    unsigned short* h1Bf   = (unsigned short*)(wsb + allocB((size_t)NN * 128 * 2));
    unsigned short* h2Bf   = (unsigned short*)(wsb + allocB((size_t)NN * 128 * 2));
    unsigned char*  U8     = (unsigned char*)(wsb + allocB((size_t)NN * 128));
    unsigned char*  naF8   = (unsigned char*)(wsb + allocB((size_t)NN * 128));
    unsigned char*  h1F8   = (unsigned char*)(wsb + allocB((size_t)NN * 128));
    unsigned char*  h2F8   = (unsigned char*)(wsb + allocB((size_t)NN * 128));
    float* adst   = (float*)(wsb + allocB((size_t)NN * 4));
    float* aD     = (float*)(wsb + allocB((size_t)NN * 4));
    float* bS     = (float*)(wsb + allocB((size_t)NN * 4));
    (void)ws_size;

    float* out0 = (float*)d_out;
    float* as0  = out0 + (size_t)NN * 128;
    float* as1  = as0 + (size_t)NN * 128;
    float* as2  = as1 + (size_t)NN * 128;
    float* g0   = out0 + (size_t)4 * NN * 128;
    float* avg  = out0 + (size_t)5 * NN * 128;

    PackArgs pa;
    pa.d[0] = { fc1_w,    Bfc1,   128, 128, 0 };
    pa.d[1] = { attend_w, Batt,   128, 128, 0 };
    pa.d[2] = { fc2_w,    BW2a,   128, 144, 0 };
    pa.d[3] = { gih1,     Bgih1,  384, 128, 0 };
    pa.d[4] = { ghh1,     Bghh1,  384, 128, 0 };
    pa.d[5] = { fc2v2_w,  Bfc2v2, 128, 128, 0 };
    pa.d[6] = { gih2,     Bgih2,  384, 128, 0 };
    pa.d[7] = { ghh2,     Bghh2,  384, 128, 0 };
    pa.d[8] = { lin_w,    Blin,   128, 128, 0 };
    pa.d[9] = { fc2_w,    BW2b,   0,   0,   1 };
    k_pack<<<dim3(24, 10), 256, 0, stream>>>(pa);

    const int GB = NN / 16;     // 1250

    // ---- V1 front ----
    k_v1_front<<<GB, 256, 0, stream>>>(atom, Bfc1, BW2a, fc1_b, fc2_b, att_w,
                                       g0, naBf, naF8, U8, adst);
    // ---- V1: fused logits + agg + GRU + front(layer2) ----
    k_gru<0, 1, 0><<<GB, 512, 0, stream>>>(
        nullptr, nullptr, nullptr,
        bond, BW2b, att_w, att_b, adst, U8,
        esrc, naF8,
        Batt, attend_b,
        Bgih1, Bghh1, bih1, bhh1, naBf, as0, h1Bf, h1F8,
        fc1v2_w, aD, bS,
        nullptr, nullptr, nullptr, nullptr, nullptr, nullptr);

    // ---- V2 layer 2 ----
    k_gru<1, 1, 0><<<GB, 512, 0, stream>>>(
        aD, bS, fc1v2_b,
        nullptr, nullptr, nullptr, nullptr, nullptr, nullptr,
        esrc, h1F8,
        Bfc2v2, fc2v2_b,
        Bgih2, Bghh2, bih2, bhh2, h1Bf, as1, h2Bf, h2F8,
        fc1v2_w, aD, bS,
        nullptr, nullptr, nullptr, nullptr, nullptr, nullptr);

    // ---- V2 layer 3 + final ----
    k_gru<1, 0, 1><<<GB, 512, 0, stream>>>(
        aD, bS, fc1v2_b,
        nullptr, nullptr, nullptr, nullptr, nullptr, nullptr,
        esrc, h2F8,
        Bfc2v2, fc2v2_b,
        Bgih2, Bghh2, bih2, bhh2, h2Bf, as2, nullptr, nullptr,
        nullptr, nullptr, nullptr,
        as0, as1, Blin, lin_b, avg, out0);
}